// Round 9
// baseline (189.548 us; speedup 1.0000x reference)
//
#include <hip/hip_runtime.h>

typedef __attribute__((ext_vector_type(8))) short short8;
typedef __attribute__((ext_vector_type(4))) float floatx4;
typedef unsigned short u16;
typedef unsigned int u32;

#define NB 8
#define CI 512
#define CO 512
#define HH 64
#define WW 64
#define HP 66
#define WP 66

__device__ __forceinline__ u16 f2bf(float f) {
  u32 u = __builtin_bit_cast(u32, f);
  u += 0x7fffu + ((u >> 16) & 1u);
  return (u16)(u >> 16);
}

__device__ __forceinline__ void gload16(const void* g, void* l) {
  __builtin_amdgcn_global_load_lds(
      (const __attribute__((address_space(1))) unsigned int*)g,
      (__attribute__((address_space(3))) unsigned int*)l, 16, 0, 0);
}

// s[b,i] = coef * dot(y[b,:], affine_w[i,:]) + affine_b[i] + 1
__global__ __launch_bounds__(256) void k_style(
    const float* __restrict__ y, const float* __restrict__ aw,
    const float* __restrict__ ab, float* __restrict__ s)
{
  const int wid = blockIdx.x * 4 + (threadIdx.x >> 6);
  const int lane = threadIdx.x & 63;
  const int b = wid >> 9, i = wid & 511;
  float sum = 0.f;
  #pragma unroll
  for (int j = 0; j < 8; ++j) {
    const int k = lane + (j << 6);
    sum += y[b * CI + k] * aw[i * CI + k];
  }
  #pragma unroll
  for (int off = 32; off; off >>= 1) sum += __shfl_xor(sum, off);
  if (lane == 0) s[wid] = sum * 0.044194173824159216f + ab[i] + 1.0f;
}

// fused: wsum[o,i] = sum_t weight[o,i,t]^2 ; wb[(o*9+t)*512+i] = bf16(weight[o,i,t])
__global__ __launch_bounds__(256) void k_wprep(
    const float* __restrict__ wt, float* __restrict__ wsum, u16* __restrict__ wbv)
{
  const int idx = blockIdx.x * 256 + threadIdx.x;   // o*512+i
  const int i = idx & 511;
  const int o = idx >> 9;
  const float* p = wt + (size_t)idx * 9;
  float v[9];
  float sum = 0.f;
  #pragma unroll
  for (int t = 0; t < 9; ++t) { v[t] = p[t]; sum += v[t] * v[t]; }
  wsum[idx] = sum;
  #pragma unroll
  for (int t = 0; t < 9; ++t) wbv[(((o * 9 + t) << 9) | i)] = f2bf(v[t]);
}

// d[b,o] = rsqrt(sum_i wsum[o,i]*s[b,i]^2 + 1e-4)
__global__ __launch_bounds__(256) void k_demod(
    const float* __restrict__ wsum, const float* __restrict__ s,
    float* __restrict__ d)
{
  const int wid = blockIdx.x * 4 + (threadIdx.x >> 6);
  const int lane = threadIdx.x & 63;
  const int b = wid >> 9, o = wid & 511;
  float sum = 0.f;
  #pragma unroll
  for (int j = 0; j < 8; ++j) {
    const int i = lane + (j << 6);
    const float sv = s[b * CI + i];
    sum += wsum[o * CI + i] * sv * sv;
  }
  #pragma unroll
  for (int off = 32; off; off >>= 1) sum += __shfl_xor(sum, off);
  if (lane == 0) d[wid] = rsqrtf(sum + 1e-4f);
}

// xs[b, h+1, w+1, i] (NHWC, 66x66 padded, bf16) = x[b,i,h,w] * s[b,i]
// also zeroes its own slice of the halo border.
__global__ __launch_bounds__(256) void k_xform(
    const float* __restrict__ x, const float* __restrict__ s,
    u16* __restrict__ xs)
{
  __shared__ __align__(16) u16 lds[64 * 72];
  const int blk = blockIdx.x;          // ((b*64+h)*8 + ic)
  const int ic = blk & 7;
  const int h = (blk >> 3) & 63;
  const int b = blk >> 9;
  const int i0 = ic << 6;
  const int t = threadIdx.x;
  const int w = t & 63;
  const int i4 = t >> 6;
  #pragma unroll
  for (int p = 0; p < 16; ++p) {
    const int ii = i4 + (p << 2);
    const float xv = x[((size_t)(b * CI + i0 + ii) * HH + h) * WW + w];
    const float sv = s[b * CI + i0 + ii];
    lds[w * 72 + ii] = f2bf(xv * sv);
  }
  const uint4 z4 = {0u, 0u, 0u, 0u};
  if (t < 16) {
    const int wside = (t < 8) ? 0 : 65;
    const int q = t & 7;
    *(uint4*)&xs[((size_t)(b * HP + h + 1) * WP + wside) * CI + i0 + (q << 3)] = z4;
  }
  if (h == 0) {
    for (int idx = t; idx < 2 * 66 * 8; idx += 256) {
      const int row = (idx < 528) ? 0 : 65;
      const int rem = (idx < 528) ? idx : idx - 528;
      const int wz = rem >> 3;
      const int q = rem & 7;
      *(uint4*)&xs[((size_t)(b * HP + row) * WP + wz) * CI + i0 + (q << 3)] = z4;
    }
  }
  __syncthreads();
  const int w2 = t >> 2;
  const int q = t & 3;
  const uint4* src = (const uint4*)&lds[w2 * 72 + (q << 4)];
  const uint4 v0 = src[0];
  const uint4 v1 = src[1];
  u16* dst = xs + ((size_t)(b * HP + h + 1) * WP + (w2 + 1)) * CI + i0 + (q << 4);
  *(uint4*)dst = v0;
  *((uint4*)dst + 1) = v1;
}

// ---------------------------------------------------------------------------
// implicit-GEMM conv: DUAL-BLOCK async design.
// BM=256 (O), BN=128 (pixels = 2 rows), BK=32, K = 144 tiles of 32.
// Grid = 32(nt) x 2(mt) x 8(b) = 512 blocks  (R8 bug: launched 1024 -> OOB).
// 256 threads, 4 waves (2M x 2N), wave tile 128x64 (acc 8x4 f32x4 = 128).
// LDS 48 KB/block -> 2 blocks/CU, two INDEPENDENT barrier domains: one
// block's read/stage window overlaps the other's MFMA window.
// Swizzle: BK=32 row = 4x16B slots; stored_slot = (slot + (row>>1)) & 3.
// ds_read: exactly 2 lanes/bank (free, m136). Applied both-sides.
// Per tile: {12 ds_read | bar | 16 MFMA | lgkmcnt(0) | bar |
//            stage t+2 (6 gloads, same buf) | 16 MFMA | vmcnt(6) | bar}
// ---------------------------------------------------------------------------
__global__ __launch_bounds__(256, 2) void k_conv(
    const u16* __restrict__ xs, const u16* __restrict__ wb,
    const float* __restrict__ dmod, const float* __restrict__ bias,
    float* __restrict__ out)
{
  __shared__ __align__(16) u16 lA[2 * 8192];   // [buf][256][32]
  __shared__ __align__(16) u16 lB[2 * 4096];   // [buf][128][32]

  // bijective XCD swizzle (512 % 8 == 0)
  const int blk0 = blockIdx.x;
  const int blk = (blk0 & 7) * 64 + (blk0 >> 3);
  const int nt = blk & 31;
  const int mt = (blk >> 5) & 1;
  const int b  = blk >> 6;
  const int ob = mt << 8;
  const int p0 = nt << 7;            // 128 pixels = 2 output rows

  const int tid = threadIdx.x;
  const int wid = tid >> 6;          // 0..3
  const int lane = tid & 63;
  const int col = lane & 15;
  const int k8  = lane >> 4;         // 0..3 (k-slot)
  const int wr  = wid >> 1;          // wave M (0..1)
  const int wc  = wid & 1;           // wave N (0..1)

  // --- staging geometry: each gload16 covers 16 rows x 4 slots (1 KB) ---
  // lane -> (row_in_group = lane>>2, stored_slot = lane&3)
  // rot = (row>>1)&3 reduces to (lane>>3)&3 (group bases are multiples of 16)
  const int rot4 = (lane >> 3) & 3;
  const int sslot = ((lane & 3) - rot4) & 3;      // source slot (pre-rotate)
  const int rowin = lane >> 2;                    // 0..15

  // A: 4 gloads/wave, gload g covers rows wid*64 + g*16 .. +15
  u32 aoffs[4], aldst[4];
  #pragma unroll
  for (int g = 0; g < 4; ++g) {
    const int row = wid * 64 + g * 16 + rowin;
    aoffs[g] = (u32)((ob + row) * 4608 + sslot * 8);
    aldst[g] = (u32)((wid * 4 + g) * 512 + lane * 8);
  }
  // B: 2 gloads/wave, gload g covers rows wid*32 + g*16 .. +15
  u32 boffs[2], bldst[2];
  #pragma unroll
  for (int g = 0; g < 2; ++g) {
    const int row = wid * 32 + g * 16 + rowin;
    const int p = p0 + row;
    boffs[g] = (u32)(((b * HP + (p >> 6)) * WP + (p & 63)) * 512 + sslot * 8);
    bldst[g] = (u32)((wid * 2 + g) * 512 + lane * 8);
  }

  // --- ds_read geometry: logical k-slot k8 stored at (k8 + (col>>1)) & 3 ---
  const u32 rdslot = (u32)(((k8 + (col >> 1)) & 3) * 8);
  const u32 aRead = (u32)((wr * 128 + col) * 32) + rdslot;   // + m*512
  const u32 bRead = (u32)((wc * 64 + col) * 32) + rdslot;    // + n*512

  floatx4 acc[8][4];
  #pragma unroll
  for (int m = 0; m < 8; ++m)
    #pragma unroll
    for (int n = 0; n < 4; ++n)
      acc[m][n] = (floatx4){0.f, 0.f, 0.f, 0.f};

  short8 av[8], bv[4];

#define STAGE(T, BUF) do {                                                    \
    const int t_ = (T);                                                       \
    const int tap_ = t_ >> 4;                                                 \
    const int kh_ = tap_ / 3;                                                 \
    const int kw_ = tap_ - kh_ * 3;                                           \
    const u32 at_ = (u32)(t_ << 5);                                           \
    const u32 bt_ = (u32)(((kh_ * WP + kw_) << 9) + ((t_ & 15) << 5));        \
    _Pragma("unroll")                                                         \
    for (int g = 0; g < 4; ++g)                                               \
      gload16(wb + aoffs[g] + at_, &lA[((BUF) << 13) + aldst[g]]);            \
    _Pragma("unroll")                                                         \
    for (int g = 0; g < 2; ++g)                                               \
      gload16(xs + boffs[g] + bt_, &lB[((BUF) << 12) + bldst[g]]);            \
  } while (0)

#define READS(BUF) do {                                                       \
    const u16* pA = lA + ((BUF) << 13) + aRead;                               \
    const u16* pB = lB + ((BUF) << 12) + bRead;                               \
    _Pragma("unroll")                                                         \
    for (int m = 0; m < 8; ++m) av[m] = *(const short8*)(pA + m * 512);       \
    _Pragma("unroll")                                                         \
    for (int n = 0; n < 4; ++n) bv[n] = *(const short8*)(pB + n * 512);       \
  } while (0)

#define MFMA_H(H) do {                                                        \
    _Pragma("unroll")                                                         \
    for (int n = 0; n < 4; ++n)                                               \
      _Pragma("unroll")                                                       \
      for (int m = 0; m < 4; ++m)                                             \
        acc[(H)*4+m][n] = __builtin_amdgcn_mfma_f32_16x16x32_bf16(            \
            av[(H)*4+m], bv[n], acc[(H)*4+m][n], 0, 0, 0);                    \
  } while (0)

#define SBAR __builtin_amdgcn_s_barrier()
#define SCH0 __builtin_amdgcn_sched_barrier(0)

#define TILE(T, BUF, DOSTAGE, WMODE) do {                                     \
    READS(BUF);                                                               \
    SBAR;                                                                     \
    __builtin_amdgcn_s_setprio(1); MFMA_H(0); __builtin_amdgcn_s_setprio(0);  \
    asm volatile("s_waitcnt lgkmcnt(0)" ::: "memory");                        \
    SBAR;                                                                     \
    SCH0;                                                                     \
    if (DOSTAGE) STAGE((T) + 2, BUF);                                         \
    __builtin_amdgcn_s_setprio(1); MFMA_H(1); __builtin_amdgcn_s_setprio(0);  \
    if (WMODE == 1)      asm volatile("s_waitcnt vmcnt(6)" ::: "memory");     \
    else if (WMODE == 2) asm volatile("s_waitcnt vmcnt(0)" ::: "memory");     \
    if (WMODE != 0) SBAR;                                                     \
  } while (0)

  // prologue: stage tiles 0,1; vmcnt(6) -> tile 0 landed (tile 1 in flight)
  STAGE(0, 0);
  STAGE(1, 1);
  asm volatile("s_waitcnt vmcnt(6)" ::: "memory");
  SBAR;

  for (int j = 0; j < 71; ++j) {
    TILE(2 * j,     0, 1, 1);
    TILE(2 * j + 1, 1, 1, 1);
  }
  TILE(142, 0, 0, 2);
  TILE(143, 1, 0, 0);

#undef STAGE
#undef READS
#undef MFMA_H
#undef TILE
#undef SBAR
#undef SCH0

  // epilogue: out = acc * d[b,o] + bias[o]; C/D: col=lane&15, row=(lane>>4)*4+r
  #pragma unroll
  for (int m = 0; m < 8; ++m) {
    #pragma unroll
    for (int r = 0; r < 4; ++r) {
      const int o = ob + (wr << 7) + (m << 4) + (k8 << 2) + r;
      const float dm = dmod[b * CO + o];
      const float bs = bias[o];
      float* po = out + (((size_t)(b * CO + o)) << 12) + p0 + (wc << 6);
      #pragma unroll
      for (int n = 0; n < 4; ++n)
        po[(n << 4) + col] = acc[m][n][r] * dm + bs;
    }
  }
}

extern "C" void kernel_launch(void* const* d_in, const int* in_sizes, int n_in,
                              void* d_out, int out_size, void* d_ws, size_t ws_size,
                              hipStream_t stream) {
  const float* x    = (const float*)d_in[0];
  const float* y    = (const float*)d_in[1];
  const float* aw   = (const float*)d_in[2];
  const float* ab   = (const float*)d_in[3];
  const float* wt   = (const float*)d_in[4];
  const float* bias = (const float*)d_in[5];
  float* out = (float*)d_out;

  char* ws = (char*)d_ws;
  const size_t XS_BYTES = (size_t)NB * HP * WP * CI * 2;     // 35,684,352
  const size_t WB_BYTES = (size_t)CO * 9 * CI * 2;           //  4,718,592
  const size_t WS_BYTES = (size_t)CO * CI * 4;               //  1,048,576
  u16* xsb    = (u16*)ws;
  u16* wbuf   = (u16*)(ws + XS_BYTES);
  float* wsum = (float*)(ws + XS_BYTES + WB_BYTES);
  float* sbuf = (float*)(ws + XS_BYTES + WB_BYTES + WS_BYTES);
  float* dbuf = sbuf + NB * CI;

  k_style<<<dim3(1024), dim3(256), 0, stream>>>(y, aw, ab, sbuf);
  k_wprep<<<dim3(1024), dim3(256), 0, stream>>>(wt, wsum, wbuf);
  k_demod<<<dim3(1024), dim3(256), 0, stream>>>(wsum, sbuf, dbuf);
  k_xform<<<dim3(4096), dim3(256), 0, stream>>>(x, sbuf, xsb);
  k_conv <<<dim3(512), dim3(256), 0, stream>>>(xsb, wbuf, dbuf, bias, out);
}

// Round 10
// 166.540 us; speedup vs baseline: 1.1382x; 1.1382x over previous
//
#include <hip/hip_runtime.h>

typedef __attribute__((ext_vector_type(8))) short short8;
typedef __attribute__((ext_vector_type(4))) float floatx4;
typedef unsigned short u16;
typedef unsigned int u32;

#define NB 8
#define CI 512
#define CO 512
#define HH 64
#define WW 64
#define HP 66
#define WP 66
#define BK 64

__device__ __forceinline__ u16 f2bf(float f) {
  u32 u = __builtin_bit_cast(u32, f);
  u += 0x7fffu + ((u >> 16) & 1u);
  return (u16)(u >> 16);
}

__device__ __forceinline__ void gload16(const void* g, void* l) {
  __builtin_amdgcn_global_load_lds(
      (const __attribute__((address_space(1))) unsigned int*)g,
      (__attribute__((address_space(3))) unsigned int*)l, 16, 0, 0);
}

// s[b,i] = coef * dot(y[b,:], affine_w[i,:]) + affine_b[i] + 1
__global__ __launch_bounds__(256) void k_style(
    const float* __restrict__ y, const float* __restrict__ aw,
    const float* __restrict__ ab, float* __restrict__ s)
{
  const int wid = blockIdx.x * 4 + (threadIdx.x >> 6);
  const int lane = threadIdx.x & 63;
  const int b = wid >> 9, i = wid & 511;
  float sum = 0.f;
  #pragma unroll
  for (int j = 0; j < 8; ++j) {
    const int k = lane + (j << 6);
    sum += y[b * CI + k] * aw[i * CI + k];
  }
  #pragma unroll
  for (int off = 32; off; off >>= 1) sum += __shfl_xor(sum, off);
  if (lane == 0) s[wid] = sum * 0.044194173824159216f + ab[i] + 1.0f;
}

// fused: wsum[o,i] = sum_t weight[o,i,t]^2 ; wb[(o*9+t)*512+i] = bf16(weight[o,i,t])
__global__ __launch_bounds__(256) void k_wprep(
    const float* __restrict__ wt, float* __restrict__ wsum, u16* __restrict__ wbv)
{
  const int idx = blockIdx.x * 256 + threadIdx.x;   // o*512+i
  const int i = idx & 511;
  const int o = idx >> 9;
  const float* p = wt + (size_t)idx * 9;
  float v[9];
  float sum = 0.f;
  #pragma unroll
  for (int t = 0; t < 9; ++t) { v[t] = p[t]; sum += v[t] * v[t]; }
  wsum[idx] = sum;
  #pragma unroll
  for (int t = 0; t < 9; ++t) wbv[(((o * 9 + t) << 9) | i)] = f2bf(v[t]);
}

// d[b,o] = rsqrt(sum_i wsum[o,i]*s[b,i]^2 + 1e-4)
__global__ __launch_bounds__(256) void k_demod(
    const float* __restrict__ wsum, const float* __restrict__ s,
    float* __restrict__ d)
{
  const int wid = blockIdx.x * 4 + (threadIdx.x >> 6);
  const int lane = threadIdx.x & 63;
  const int b = wid >> 9, o = wid & 511;
  float sum = 0.f;
  #pragma unroll
  for (int j = 0; j < 8; ++j) {
    const int i = lane + (j << 6);
    const float sv = s[b * CI + i];
    sum += wsum[o * CI + i] * sv * sv;
  }
  #pragma unroll
  for (int off = 32; off; off >>= 1) sum += __shfl_xor(sum, off);
  if (lane == 0) d[wid] = rsqrtf(sum + 1e-4f);
}

// xs[b, h+1, w+1, i] (NHWC, 66x66 padded, bf16) = x[b,i,h,w] * s[b,i]
// also zeroes its own slice of the halo border.
__global__ __launch_bounds__(256) void k_xform(
    const float* __restrict__ x, const float* __restrict__ s,
    u16* __restrict__ xs)
{
  __shared__ __align__(16) u16 lds[64 * 72];
  const int blk = blockIdx.x;          // ((b*64+h)*8 + ic)
  const int ic = blk & 7;
  const int h = (blk >> 3) & 63;
  const int b = blk >> 9;
  const int i0 = ic << 6;
  const int t = threadIdx.x;
  const int w = t & 63;
  const int i4 = t >> 6;
  #pragma unroll
  for (int p = 0; p < 16; ++p) {
    const int ii = i4 + (p << 2);
    const float xv = x[((size_t)(b * CI + i0 + ii) * HH + h) * WW + w];
    const float sv = s[b * CI + i0 + ii];
    lds[w * 72 + ii] = f2bf(xv * sv);
  }
  const uint4 z4 = {0u, 0u, 0u, 0u};
  if (t < 16) {
    const int wside = (t < 8) ? 0 : 65;
    const int q = t & 7;
    *(uint4*)&xs[((size_t)(b * HP + h + 1) * WP + wside) * CI + i0 + (q << 3)] = z4;
  }
  if (h == 0) {
    for (int idx = t; idx < 2 * 66 * 8; idx += 256) {
      const int row = (idx < 528) ? 0 : 65;
      const int rem = (idx < 528) ? idx : idx - 528;
      const int wz = rem >> 3;
      const int q = rem & 7;
      *(uint4*)&xs[((size_t)(b * HP + row) * WP + wz) * CI + i0 + (q << 3)] = z4;
    }
  }
  __syncthreads();
  const int w2 = t >> 2;
  const int q = t & 3;
  const uint4* src = (const uint4*)&lds[w2 * 72 + (q << 4)];
  const uint4 v0 = src[0];
  const uint4 v1 = src[1];
  u16* dst = xs + ((size_t)(b * HP + h + 1) * WP + (w2 + 1)) * CI + i0 + (q << 4);
  *(uint4*)dst = v0;
  *((uint4*)dst + 1) = v1;
}

// ---------------------------------------------------------------------------
// implicit-GEMM conv, PIPELINED-READS schedule, MFMA 16x16x32 bf16.
// BM=256 (O), BN=256 (pixels), BK=64, K = 72 tiles. 512 thr, 8 waves (2Mx4N).
// LDS 128 KB double-buffered, XOR slot swizzle (both-sides).
// Every ds_read issues >=2 micro-phases before its consuming MFMA (reg-rotated
// A-quarters setA/setB, B-halves b0/b1) -> lgkm waits are no-ops; LDS pipe
// runs concurrently with MFMA pipe. Only 2 barriers/tile (write-safety):
//   ph6-end: vmcnt(0)+bar  (certifies next tile's buffer fully landed;
//            also certifies all B-reads of cur buf done -> SB safe at ph7)
//   ph7-end: bar           (certifies q3 A-reads done -> SA safe at ph8)
// Stages T+2 deep: SB(T+2) at ph7, SA(T+2) at ph8 (~1.5 tiles in flight).
// ---------------------------------------------------------------------------
__global__ __launch_bounds__(512, 2) void k_conv(
    const u16* __restrict__ xs, const u16* __restrict__ wb,
    const float* __restrict__ dmod, const float* __restrict__ bias,
    float* __restrict__ out)
{
  __shared__ __align__(16) u16 lA[2 * 16384];
  __shared__ __align__(16) u16 lB[2 * 16384];

  const int blk = blockIdx.x;
  const int nt = blk & 15;
  const int mt = (blk >> 4) & 1;
  const int b  = blk >> 5;
  const int ob = mt << 8;
  const int p0 = nt << 8;

  const int tid = threadIdx.x;
  const int wid = tid >> 6;
  const int lane = tid & 63;
  const int col = lane & 15;
  const int k8  = lane >> 4;
  const int wr  = wid >> 2;          // wave M index (0..1)
  const int wc  = wid & 3;           // wave N index (0..3)

  // staging lane geometry: gload16 stages 8 rows x 8 slots (1 KB), LDS linear.
  // source column pre-swizzled: lane l fetches slot (l&7)^(l>>3) of its row.
  const int lr = lane >> 3;
  const int ls = lane & 7;
  const int swz = ls ^ lr;

  u32 aoff[4], boff[4], ldst[4];
  #pragma unroll
  for (int h2 = 0; h2 < 4; ++h2) {
    const int rowBase = ((h2 >> 1) << 7) + (wid << 4) + ((h2 & 1) << 3);
    const int rowIdx = rowBase + lr;
    aoff[h2] = (u32)((ob + rowIdx) * 4608 + (swz << 3));
    const int p = p0 + rowIdx;
    boff[h2] = (u32)(((b * HP + (p >> 6)) * WP + (p & 63)) * 512 + (swz << 3));
    ldst[h2] = (u32)(rowBase << 6);
  }

  // ds_read swizzled slot offsets: slot (kk*4+k8) ^ (row&7), row&7 == col&7
  const u32 sA0 = (u32)(((0 + k8) ^ (col & 7)) << 3);
  const u32 sA1 = (u32)(((4 + k8) ^ (col & 7)) << 3);
  const u32 aRead = (u32)((((wr << 7) + col) << 6));
  const u32 bRead = (u32)((((wc << 6) + col) << 6));

  floatx4 acc[8][4];
  #pragma unroll
  for (int m = 0; m < 8; ++m)
    #pragma unroll
    for (int n = 0; n < 4; ++n)
      acc[m][n] = (floatx4){0.f, 0.f, 0.f, 0.f};

  short8 setA[2][2], setB[2][2], b0[2][2], b1[2][2];

#define STAGE_A(T, BUF) do {                                                  \
    const u32 at_ = (u32)((T) << 6);                                          \
    _Pragma("unroll")                                                         \
    for (int g = 0; g < 4; ++g)                                               \
      gload16(wb + aoff[g] + at_, &lA[((BUF) << 14) + ldst[g]]);              \
  } while (0)

#define STAGE_B(T, BUF) do {                                                  \
    const int t_ = (T);                                                       \
    const int tap_ = t_ >> 3;                                                 \
    const int kh_ = tap_ / 3;                                                 \
    const int kw_ = tap_ - kh_ * 3;                                           \
    const u32 bt_ = (u32)(((kh_ * WP + kw_) << 9) + ((t_ & 7) << 6));         \
    _Pragma("unroll")                                                         \
    for (int g = 0; g < 4; ++g)                                               \
      gload16(xs + boff[g] + bt_, &lB[((BUF) << 14) + ldst[g]]);              \
  } while (0)

// A-quarter Q (m-frags 2Q, 2Q+1) -> SET
#define READ_Q(SET, PA, Q) do {                                               \
    _Pragma("unroll")                                                         \
    for (int mq2 = 0; mq2 < 2; ++mq2) {                                       \
      SET[mq2][0] = *(const short8*)((PA) + ((Q)*2+mq2) * 1024 + sA0);        \
      SET[mq2][1] = *(const short8*)((PA) + ((Q)*2+mq2) * 1024 + sA1);        \
    }                                                                         \
  } while (0)

// B-half NH (n-frags 2NH, 2NH+1) -> BV
#define READ_BH(BV, PB, NH) do {                                              \
    _Pragma("unroll")                                                         \
    for (int nq2 = 0; nq2 < 2; ++nq2) {                                       \
      BV[nq2][0] = *(const short8*)((PB) + (NH) * 2048 + nq2 * 1024 + sA0);   \
      BV[nq2][1] = *(const short8*)((PB) + (NH) * 2048 + nq2 * 1024 + sA1);   \
    }                                                                         \
  } while (0)

// 8 MFMA: quarter Q x B-half NH
#define MFMA_P(Q, NH, ASET, BV) do {                                          \
    _Pragma("unroll")                                                         \
    for (int kk = 0; kk < 2; ++kk)                                            \
      _Pragma("unroll")                                                       \
      for (int nq2 = 0; nq2 < 2; ++nq2)                                       \
        _Pragma("unroll")                                                     \
        for (int mq2 = 0; mq2 < 2; ++mq2)                                     \
          acc[(Q)*2+mq2][(NH)*2+nq2] = __builtin_amdgcn_mfma_f32_16x16x32_bf16(\
              ASET[mq2][kk], BV[nq2][kk], acc[(Q)*2+mq2][(NH)*2+nq2], 0,0,0); \
  } while (0)

#define SBAR __builtin_amdgcn_s_barrier()
#define PRI1 __builtin_amdgcn_s_setprio(1)
#define PRI0 __builtin_amdgcn_s_setprio(0)

// entry state: setA=q0(T), b0=B0(T), b1=B1(T) already read.
#define TILE8(T, C, FULL) do {                                                \
    const u16* pA  = lA + ((C) << 14) + aRead;                                \
    const u16* pA1 = lA + ((1 - (C)) << 14) + aRead;                          \
    const u16* pB1 = lB + ((1 - (C)) << 14) + bRead;                          \
    /* ph1 */ READ_Q(setB, pA, 1);                                            \
    PRI1; MFMA_P(0, 0, setA, b0); PRI0;                                       \
    /* ph2 */ PRI1; MFMA_P(0, 1, setA, b1); PRI0;                             \
    /* ph3 */ READ_Q(setA, pA, 2);                                            \
    PRI1; MFMA_P(1, 0, setB, b0); PRI0;                                       \
    /* ph4 */ PRI1; MFMA_P(1, 1, setB, b1); PRI0;                             \
    /* ph5 */ READ_Q(setB, pA, 3);                                            \
    PRI1; MFMA_P(2, 0, setA, b0); PRI0;                                       \
    /* ph6 */ PRI1; MFMA_P(2, 1, setA, b1); PRI0;                             \
    asm volatile("s_waitcnt vmcnt(0)" ::: "memory");                          \
    SBAR;                                                                     \
    /* ph7: stage B(T+2) into just-certified-free region; prefetch T+1 */     \
    if (FULL) STAGE_B((T) + 2, C);                                            \
    READ_Q(setA, pA1, 0);                                                     \
    PRI1; MFMA_P(3, 0, setB, b0); PRI0;                                       \
    READ_BH(b0, pB1, 0);         /* after last b0 use: WAR-ordered */         \
    SBAR;                                                                     \
    /* ph8 */                                                                 \
    if (FULL) STAGE_A((T) + 2, C);                                            \
    PRI1; MFMA_P(3, 1, setB, b1); PRI0;                                       \
    READ_BH(b1, pB1, 1);         /* after last b1 use */                      \
  } while (0)

  // prologue: stage tiles 0,1; wait tile 0 (tile 1's 8 stay in flight);
  // pre-read q0/b0/b1 of tile 0.
  STAGE_B(0, 0); STAGE_A(0, 0);
  STAGE_B(1, 1); STAGE_A(1, 1);
  asm volatile("s_waitcnt vmcnt(8)" ::: "memory");
  SBAR;
  {
    const u16* pA0 = lA + aRead;
    const u16* pB0 = lB + bRead;
    READ_Q(setA, pA0, 0);
    READ_BH(b0, pB0, 0);
    READ_BH(b1, pB0, 1);
  }

  for (int j = 0; j < 35; ++j) {
    TILE8(2 * j,     0, 1);
    TILE8(2 * j + 1, 1, 1);
  }
  TILE8(70, 0, 0);
  TILE8(71, 1, 0);

#undef STAGE_A
#undef STAGE_B
#undef READ_Q
#undef READ_BH
#undef MFMA_P
#undef TILE8
#undef SBAR
#undef PRI1
#undef PRI0

  // epilogue: out = acc * d[b,o] + bias[o]; C/D: col=lane&15, row=(lane>>4)*4+r
  #pragma unroll
  for (int m = 0; m < 8; ++m) {
    #pragma unroll
    for (int r = 0; r < 4; ++r) {
      const int o = ob + (wr << 7) + (m << 4) + (k8 << 2) + r;
      const float dm = dmod[b * CO + o];
      const float bs = bias[o];
      float* po = out + (((size_t)(b * CO + o)) << 12) + p0 + (wc << 6);
      #pragma unroll
      for (int n = 0; n < 4; ++n)
        po[(n << 4) + col] = acc[m][n][r] * dm + bs;
    }
  }
}

extern "C" void kernel_launch(void* const* d_in, const int* in_sizes, int n_in,
                              void* d_out, int out_size, void* d_ws, size_t ws_size,
                              hipStream_t stream) {
  const float* x    = (const float*)d_in[0];
  const float* y    = (const float*)d_in[1];
  const float* aw   = (const float*)d_in[2];
  const float* ab   = (const float*)d_in[3];
  const float* wt   = (const float*)d_in[4];
  const float* bias = (const float*)d_in[5];
  float* out = (float*)d_out;

  char* ws = (char*)d_ws;
  const size_t XS_BYTES = (size_t)NB * HP * WP * CI * 2;     // 35,684,352
  const size_t WB_BYTES = (size_t)CO * 9 * CI * 2;           //  4,718,592
  const size_t WS_BYTES = (size_t)CO * CI * 4;               //  1,048,576
  u16* xsb    = (u16*)ws;
  u16* wbuf   = (u16*)(ws + XS_BYTES);
  float* wsum = (float*)(ws + XS_BYTES + WB_BYTES);
  float* sbuf = (float*)(ws + XS_BYTES + WB_BYTES + WS_BYTES);
  float* dbuf = sbuf + NB * CI;

  k_style<<<dim3(1024), dim3(256), 0, stream>>>(y, aw, ab, sbuf);
  k_wprep<<<dim3(1024), dim3(256), 0, stream>>>(wt, wsum, wbuf);
  k_demod<<<dim3(1024), dim3(256), 0, stream>>>(wsum, sbuf, dbuf);
  k_xform<<<dim3(4096), dim3(256), 0, stream>>>(x, sbuf, xsb);
  k_conv <<<dim3(256), dim3(512), 0, stream>>>(xsb, wbuf, dbuf, bias, out);
}

// Round 11
// 158.865 us; speedup vs baseline: 1.1931x; 1.0483x over previous
//
#include <hip/hip_runtime.h>

typedef __attribute__((ext_vector_type(8))) short short8;
typedef __attribute__((ext_vector_type(4))) float floatx4;
typedef unsigned short u16;
typedef unsigned int u32;

#define NB 8
#define CI 512
#define CO 512
#define HH 64
#define WW 64
#define HP 66
#define WP 66
#define BK 64

__device__ __forceinline__ u16 f2bf(float f) {
  u32 u = __builtin_bit_cast(u32, f);
  u += 0x7fffu + ((u >> 16) & 1u);
  return (u16)(u >> 16);
}

__device__ __forceinline__ void gload16(const void* g, void* l) {
  __builtin_amdgcn_global_load_lds(
      (const __attribute__((address_space(1))) unsigned int*)g,
      (__attribute__((address_space(3))) unsigned int*)l, 16, 0, 0);
}

// fused prep1: blocks 0..1023 -> style s[b,i]; blocks 1024..2047 -> wprep.
__global__ __launch_bounds__(256) void k_prep1(
    const float* __restrict__ y, const float* __restrict__ aw,
    const float* __restrict__ ab, float* __restrict__ s,
    const float* __restrict__ wt, float* __restrict__ wsum,
    u16* __restrict__ wbv)
{
  if (blockIdx.x < 1024) {
    // s[b,i] = coef * dot(y[b,:], affine_w[i,:]) + affine_b[i] + 1
    const int wid = blockIdx.x * 4 + (threadIdx.x >> 6);
    const int lane = threadIdx.x & 63;
    const int b = wid >> 9, i = wid & 511;
    float sum = 0.f;
    #pragma unroll
    for (int j = 0; j < 8; ++j) {
      const int k = lane + (j << 6);
      sum += y[b * CI + k] * aw[i * CI + k];
    }
    #pragma unroll
    for (int off = 32; off; off >>= 1) sum += __shfl_xor(sum, off);
    if (lane == 0) s[wid] = sum * 0.044194173824159216f + ab[i] + 1.0f;
  } else {
    // wsum[o,i] = sum_t w^2 ; wb[(o*9+t)*512+i] = bf16(w)
    const int idx = (blockIdx.x - 1024) * 256 + threadIdx.x;   // o*512+i
    const int i = idx & 511;
    const int o = idx >> 9;
    const float* p = wt + (size_t)idx * 9;
    float v[9];
    float sum = 0.f;
    #pragma unroll
    for (int t = 0; t < 9; ++t) { v[t] = p[t]; sum += v[t] * v[t]; }
    wsum[idx] = sum;
    #pragma unroll
    for (int t = 0; t < 9; ++t) wbv[(((o * 9 + t) << 9) | i)] = f2bf(v[t]);
  }
}

// fused: blocks 0..4095 -> xform (xs build + halo zero); 4096..5119 -> demod.
__global__ __launch_bounds__(256) void k_xfd(
    const float* __restrict__ x, const float* __restrict__ s,
    u16* __restrict__ xs, const float* __restrict__ wsum,
    float* __restrict__ d)
{
  __shared__ __align__(16) u16 lds[64 * 72];
  if (blockIdx.x >= 4096) {
    // d[b,o] = rsqrt(sum_i wsum[o,i]*s[b,i]^2 + 1e-4)
    const int wid = (blockIdx.x - 4096) * 4 + (threadIdx.x >> 6);
    const int lane = threadIdx.x & 63;
    const int b = wid >> 9, o = wid & 511;
    float sum = 0.f;
    #pragma unroll
    for (int j = 0; j < 8; ++j) {
      const int i = lane + (j << 6);
      const float sv = s[b * CI + i];
      sum += wsum[o * CI + i] * sv * sv;
    }
    #pragma unroll
    for (int off = 32; off; off >>= 1) sum += __shfl_xor(sum, off);
    if (lane == 0) d[wid] = rsqrtf(sum + 1e-4f);
    return;
  }
  const int blk = blockIdx.x;          // ((b*64+h)*8 + ic)
  const int ic = blk & 7;
  const int h = (blk >> 3) & 63;
  const int b = blk >> 9;
  const int i0 = ic << 6;
  const int t = threadIdx.x;
  const int w = t & 63;
  const int i4 = t >> 6;
  #pragma unroll
  for (int p = 0; p < 16; ++p) {
    const int ii = i4 + (p << 2);
    const float xv = x[((size_t)(b * CI + i0 + ii) * HH + h) * WW + w];
    const float sv = s[b * CI + i0 + ii];
    lds[w * 72 + ii] = f2bf(xv * sv);
  }
  const uint4 z4 = {0u, 0u, 0u, 0u};
  if (t < 16) {
    const int wside = (t < 8) ? 0 : 65;
    const int q = t & 7;
    *(uint4*)&xs[((size_t)(b * HP + h + 1) * WP + wside) * CI + i0 + (q << 3)] = z4;
  }
  if (h == 0) {
    for (int idx = t; idx < 2 * 66 * 8; idx += 256) {
      const int row = (idx < 528) ? 0 : 65;
      const int rem = (idx < 528) ? idx : idx - 528;
      const int wz = rem >> 3;
      const int q = rem & 7;
      *(uint4*)&xs[((size_t)(b * HP + row) * WP + wz) * CI + i0 + (q << 3)] = z4;
    }
  }
  __syncthreads();
  const int w2 = t >> 2;
  const int q = t & 3;
  const uint4* src = (const uint4*)&lds[w2 * 72 + (q << 4)];
  const uint4 v0 = src[0];
  const uint4 v1 = src[1];
  u16* dst = xs + ((size_t)(b * HP + h + 1) * WP + (w2 + 1)) * CI + i0 + (q << 4);
  *(uint4*)dst = v0;
  *((uint4*)dst + 1) = v1;
}

// ---------------------------------------------------------------------------
// implicit-GEMM conv, m201-style 8-phase schedule, MFMA 16x16x32 bf16.
// (R7 champion kernel + XCD-locality swizzle.)
// BM=256 (O), BN=256 (pixels), BK=64, K = 9 taps x 512 = 72 tiles.
// XCD swizzle: logical order mt-outer (lblk = mt<<7 | b<<4 | nt); XCD k gets
// lblk in [32k, 32k+32) -> all 32 blocks on an XCD share one mt => the 2.3 MB
// A-panel stays L2-resident (predict FETCH 134 -> ~95 MB).
// ---------------------------------------------------------------------------
__global__ __launch_bounds__(512, 2) void k_conv(
    const u16* __restrict__ xs, const u16* __restrict__ wb,
    const float* __restrict__ dmod, const float* __restrict__ bias,
    float* __restrict__ out)
{
  __shared__ __align__(16) u16 lA[2 * 16384];
  __shared__ __align__(16) u16 lB[2 * 16384];

  // XCD-locality swizzle: dispatch round-robins blk0%8 across XCDs.
  const int blk0 = blockIdx.x;
  const int lblk = ((blk0 & 7) << 5) + (blk0 >> 3);
  const int mt = lblk >> 7;
  const int b  = (lblk >> 4) & 7;
  const int nt = lblk & 15;
  const int ob = mt << 8;
  const int p0 = nt << 8;

  const int tid = threadIdx.x;
  const int wid = tid >> 6;
  const int lane = tid & 63;
  const int col = lane & 15;
  const int k8  = lane >> 4;
  const int wr  = wid >> 2;          // wave M index (0..1)
  const int wc  = wid & 3;           // wave N index (0..3)

  // staging lane geometry: each gload16 stages 8 rows x 8 slots (1 KB).
  // source column pre-swizzled: lane l fetches slot (l&7)^(l>>3) of its row.
  const int lr = lane >> 3;
  const int ls = lane & 7;
  const int swz = ls ^ lr;

  // half-tile staging: half h (128 rows), sub g (2 gloads); idx = h*2+g.
  // rowIdx = h*128 + wid*16 + g*8 + lr  (8 waves x 16 rows = 128)
  u32 aoff[4], boff[4], ldst[4];
  #pragma unroll
  for (int h2 = 0; h2 < 4; ++h2) {
    const int rowBase = ((h2 >> 1) << 7) + (wid << 4) + ((h2 & 1) << 3);
    const int rowIdx = rowBase + lr;
    aoff[h2] = (u32)((ob + rowIdx) * 4608 + (swz << 3));
    const int p = p0 + rowIdx;
    boff[h2] = (u32)(((b * HP + (p >> 6)) * WP + (p & 63)) * 512 + (swz << 3));
    ldst[h2] = (u32)(rowBase << 6);
  }

  // ds_read swizzled slot offsets: slot (kk*4+k8) ^ (row&7), row&7 == col&7
  const u32 sA0 = (u32)(((0 + k8) ^ (col & 7)) << 3);
  const u32 sA1 = (u32)(((4 + k8) ^ (col & 7)) << 3);
  const u32 aRead = (u32)((((wr << 7) + col) << 6));
  const u32 bRead = (u32)((((wc << 6) + col) << 6));

  floatx4 acc[8][4];
  #pragma unroll
  for (int m = 0; m < 8; ++m)
    #pragma unroll
    for (int n = 0; n < 4; ++n)
      acc[m][n] = (floatx4){0.f, 0.f, 0.f, 0.f};

  short8 a0[4][2], b0[2][2], b1[2][2];

#define SA(TILE, H, BUF) do {                                                 \
    const u32 at_ = (u32)((TILE) << 6);                                       \
    gload16(wb + aoff[(H)*2+0] + at_, &lA[((BUF) << 14) + ldst[(H)*2+0]]);    \
    gload16(wb + aoff[(H)*2+1] + at_, &lA[((BUF) << 14) + ldst[(H)*2+1]]);    \
  } while (0)

#define SB(TILE, H, BUF) do {                                                 \
    const int t_ = (TILE);                                                    \
    const int tap_ = t_ >> 3;                                                 \
    const int kh_ = tap_ / 3;                                                 \
    const int kw_ = tap_ - kh_ * 3;                                           \
    const u32 bt_ = (u32)(((kh_ * WP + kw_) << 9) + ((t_ & 7) << 6));         \
    gload16(xs + boff[(H)*2+0] + bt_, &lB[((BUF) << 14) + ldst[(H)*2+0]]);    \
    gload16(xs + boff[(H)*2+1] + bt_, &lB[((BUF) << 14) + ldst[(H)*2+1]]);    \
  } while (0)

#define READ_A(PA, MH) do {                                                   \
    _Pragma("unroll")                                                         \
    for (int mq = 0; mq < 4; ++mq) {                                          \
      a0[mq][0] = *(const short8*)((PA) + (MH) * 4096 + mq * 1024 + sA0);     \
      a0[mq][1] = *(const short8*)((PA) + (MH) * 4096 + mq * 1024 + sA1);     \
    }                                                                         \
  } while (0)

#define READ_B(PB, NH, BV) do {                                               \
    _Pragma("unroll")                                                         \
    for (int nq = 0; nq < 2; ++nq) {                                          \
      BV[nq][0] = *(const short8*)((PB) + (NH) * 2048 + nq * 1024 + sA0);     \
      BV[nq][1] = *(const short8*)((PB) + (NH) * 2048 + nq * 1024 + sA1);     \
    }                                                                         \
  } while (0)

#define MFMA_Q(MH, NH, BV) do {                                               \
    _Pragma("unroll")                                                         \
    for (int kk = 0; kk < 2; ++kk)                                            \
      _Pragma("unroll")                                                       \
      for (int nq = 0; nq < 2; ++nq)                                          \
        _Pragma("unroll")                                                     \
        for (int mq = 0; mq < 4; ++mq)                                        \
          acc[(MH)*4+mq][(NH)*2+nq] = __builtin_amdgcn_mfma_f32_16x16x32_bf16(\
              a0[mq][kk], BV[nq][kk], acc[(MH)*4+mq][(NH)*2+nq], 0, 0, 0);    \
  } while (0)

#define SBAR __builtin_amdgcn_s_barrier()
#define SCH0 __builtin_amdgcn_sched_barrier(0)
#define PRI1 __builtin_amdgcn_s_setprio(1)
#define PRI0 __builtin_amdgcn_s_setprio(0)

#define BODY8(T0, FULL) do {                                                  \
    const u16* pA0 = lA + aRead;                                              \
    const u16* pB0 = lB + bRead;                                              \
    const u16* pA1 = lA + 16384 + aRead;                                      \
    const u16* pB1 = lB + 16384 + bRead;                                      \
    /* ph1: quad(0,0) of tile T0 (buf0) */                                    \
    READ_A(pA0, 0); READ_B(pB0, 0, b0);                                       \
    SCH0; SA((T0) + 1, 0, 1);                                                 \
    SBAR; PRI1; MFMA_Q(0, 0, b0); PRI0; SBAR;                                 \
    /* ph2: quad(0,1) */                                                      \
    READ_B(pB0, 1, b1);                                                       \
    SCH0; SA((T0) + 1, 1, 1);                                                 \
    SBAR; PRI1; MFMA_Q(0, 1, b1); PRI0; SBAR;                                 \
    /* ph3: quad(1,1) — B(buf0) fully read after ph2 */                       \
    READ_A(pA0, 1);                                                           \
    SCH0; if (FULL) SB((T0) + 2, 0, 0);                                       \
    SBAR; PRI1; MFMA_Q(1, 1, b1); PRI0; SBAR;                                 \
    /* ph4: quad(1,0) — vmcnt: tile T0+1 fully landed */                      \
    SCH0; if (FULL) SB((T0) + 2, 1, 0);                                       \
    SBAR; PRI1; MFMA_Q(1, 0, b0); PRI0;                                       \
    if (FULL) asm volatile("s_waitcnt vmcnt(4)" ::: "memory");                \
    else      asm volatile("s_waitcnt vmcnt(0)" ::: "memory");                \
    SBAR;                                                                     \
    /* ph5: quad(0,0) of tile T0+1 (buf1) — A(buf0) fully read after ph3 */   \
    READ_A(pA1, 0); READ_B(pB1, 0, b0);                                       \
    SCH0; if (FULL) SA((T0) + 2, 0, 0);                                       \
    SBAR; PRI1; MFMA_Q(0, 0, b0); PRI0; SBAR;                                 \
    /* ph6: quad(0,1) */                                                      \
    READ_B(pB1, 1, b1);                                                       \
    SCH0; if (FULL) SA((T0) + 2, 1, 0);                                       \
    SBAR; PRI1; MFMA_Q(0, 1, b1); PRI0; SBAR;                                 \
    /* ph7: quad(1,1) — B(buf1) fully read after ph6 */                       \
    READ_A(pA1, 1);                                                           \
    SCH0; if (FULL) SB((T0) + 3, 0, 1);                                       \
    SBAR; PRI1; MFMA_Q(1, 1, b1); PRI0; SBAR;                                 \
    /* ph8: quad(1,0) — vmcnt: tile T0+2 fully landed */                      \
    SCH0; if (FULL) SB((T0) + 3, 1, 1);                                       \
    SBAR; PRI1; MFMA_Q(1, 0, b0); PRI0;                                       \
    if (FULL) asm volatile("s_waitcnt vmcnt(4)" ::: "memory");                \
    SBAR;                                                                     \
  } while (0)

  // prologue: tile0 full + tile1-B; vmcnt(4) leaves tile1-B in flight.
  SB(0, 0, 0); SB(0, 1, 0); SA(0, 0, 0); SA(0, 1, 0);
  SB(1, 0, 1); SB(1, 1, 1);
  asm volatile("s_waitcnt vmcnt(4)" ::: "memory");
  SCH0;
  SBAR;

  for (int j = 0; j < 35; ++j) BODY8(j * 2, 1);
  BODY8(70, 0);

#undef SA
#undef SB
#undef READ_A
#undef READ_B
#undef MFMA_Q
#undef BODY8
#undef SBAR
#undef SCH0
#undef PRI1
#undef PRI0

  // epilogue: out = acc * d[b,o] + bias[o]; C/D: col=lane&15, row=(lane>>4)*4+r
  #pragma unroll
  for (int m = 0; m < 8; ++m) {
    #pragma unroll
    for (int r = 0; r < 4; ++r) {
      const int o = ob + (wr << 7) + (m << 4) + (k8 << 2) + r;
      const float dm = dmod[b * CO + o];
      const float bs = bias[o];
      float* po = out + (((size_t)(b * CO + o)) << 12) + p0 + (wc << 6);
      #pragma unroll
      for (int n = 0; n < 4; ++n)
        po[(n << 4) + col] = acc[m][n][r] * dm + bs;
    }
  }
}

extern "C" void kernel_launch(void* const* d_in, const int* in_sizes, int n_in,
                              void* d_out, int out_size, void* d_ws, size_t ws_size,
                              hipStream_t stream) {
  const float* x    = (const float*)d_in[0];
  const float* y    = (const float*)d_in[1];
  const float* aw   = (const float*)d_in[2];
  const float* ab   = (const float*)d_in[3];
  const float* wt   = (const float*)d_in[4];
  const float* bias = (const float*)d_in[5];
  float* out = (float*)d_out;

  char* ws = (char*)d_ws;
  const size_t XS_BYTES = (size_t)NB * HP * WP * CI * 2;     // 35,684,352
  const size_t WB_BYTES = (size_t)CO * 9 * CI * 2;           //  4,718,592
  const size_t WS_BYTES = (size_t)CO * CI * 4;               //  1,048,576
  u16* xsb    = (u16*)ws;
  u16* wbuf   = (u16*)(ws + XS_BYTES);
  float* wsum = (float*)(ws + XS_BYTES + WB_BYTES);
  float* sbuf = (float*)(ws + XS_BYTES + WB_BYTES + WS_BYTES);
  float* dbuf = sbuf + NB * CI;

  k_prep1<<<dim3(2048), dim3(256), 0, stream>>>(y, aw, ab, sbuf, wt, wsum, wbuf);
  k_xfd  <<<dim3(5120), dim3(256), 0, stream>>>(x, sbuf, xsb, wsum, dbuf);
  k_conv <<<dim3(256), dim3(512), 0, stream>>>(xsb, wbuf, dbuf, bias, out);
}

// Round 12
// 154.242 us; speedup vs baseline: 1.2289x; 1.0300x over previous
//
#include <hip/hip_runtime.h>

typedef __attribute__((ext_vector_type(8))) short short8;
typedef __attribute__((ext_vector_type(4))) float floatx4;
typedef unsigned short u16;
typedef unsigned int u32;

#define NB 8
#define CI 512
#define CO 512
#define HH 64
#define WW 64
#define HP 66
#define WP 66
#define BK 64

__device__ __forceinline__ u16 f2bf(float f) {
  u32 u = __builtin_bit_cast(u32, f);
  u += 0x7fffu + ((u >> 16) & 1u);
  return (u16)(u >> 16);
}

__device__ __forceinline__ void gload16(const void* g, void* l) {
  __builtin_amdgcn_global_load_lds(
      (const __attribute__((address_space(1))) unsigned int*)g,
      (__attribute__((address_space(3))) unsigned int*)l, 16, 0, 0);
}

// fused prep1: blocks 0..1023 -> style s[b,i]; blocks 1024..2047 -> wprep.
__global__ __launch_bounds__(256) void k_prep1(
    const float* __restrict__ y, const float* __restrict__ aw,
    const float* __restrict__ ab, float* __restrict__ s,
    const float* __restrict__ wt, float* __restrict__ wsum,
    u16* __restrict__ wbv)
{
  if (blockIdx.x < 1024) {
    const int wid = blockIdx.x * 4 + (threadIdx.x >> 6);
    const int lane = threadIdx.x & 63;
    const int b = wid >> 9, i = wid & 511;
    float sum = 0.f;
    #pragma unroll
    for (int j = 0; j < 8; ++j) {
      const int k = lane + (j << 6);
      sum += y[b * CI + k] * aw[i * CI + k];
    }
    #pragma unroll
    for (int off = 32; off; off >>= 1) sum += __shfl_xor(sum, off);
    if (lane == 0) s[wid] = sum * 0.044194173824159216f + ab[i] + 1.0f;
  } else {
    const int idx = (blockIdx.x - 1024) * 256 + threadIdx.x;   // o*512+i
    const int i = idx & 511;
    const int o = idx >> 9;
    const float* p = wt + (size_t)idx * 9;
    float v[9];
    float sum = 0.f;
    #pragma unroll
    for (int t = 0; t < 9; ++t) { v[t] = p[t]; sum += v[t] * v[t]; }
    wsum[idx] = sum;
    #pragma unroll
    for (int t = 0; t < 9; ++t) wbv[(((o * 9 + t) << 9) | i)] = f2bf(v[t]);
  }
}

// fused: blocks 0..4095 -> xform (xs build + halo zero); 4096..5119 -> demod.
__global__ __launch_bounds__(256) void k_xfd(
    const float* __restrict__ x, const float* __restrict__ s,
    u16* __restrict__ xs, const float* __restrict__ wsum,
    float* __restrict__ d)
{
  __shared__ __align__(16) u16 lds[64 * 72];
  if (blockIdx.x >= 4096) {
    const int wid = (blockIdx.x - 4096) * 4 + (threadIdx.x >> 6);
    const int lane = threadIdx.x & 63;
    const int b = wid >> 9, o = wid & 511;
    float sum = 0.f;
    #pragma unroll
    for (int j = 0; j < 8; ++j) {
      const int i = lane + (j << 6);
      const float sv = s[b * CI + i];
      sum += wsum[o * CI + i] * sv * sv;
    }
    #pragma unroll
    for (int off = 32; off; off >>= 1) sum += __shfl_xor(sum, off);
    if (lane == 0) d[wid] = rsqrtf(sum + 1e-4f);
    return;
  }
  const int blk = blockIdx.x;          // ((b*64+h)*8 + ic)
  const int ic = blk & 7;
  const int h = (blk >> 3) & 63;
  const int b = blk >> 9;
  const int i0 = ic << 6;
  const int t = threadIdx.x;
  const int w = t & 63;
  const int i4 = t >> 6;
  #pragma unroll
  for (int p = 0; p < 16; ++p) {
    const int ii = i4 + (p << 2);
    const float xv = x[((size_t)(b * CI + i0 + ii) * HH + h) * WW + w];
    const float sv = s[b * CI + i0 + ii];
    lds[w * 72 + ii] = f2bf(xv * sv);
  }
  const uint4 z4 = {0u, 0u, 0u, 0u};
  if (t < 16) {
    const int wside = (t < 8) ? 0 : 65;
    const int q = t & 7;
    *(uint4*)&xs[((size_t)(b * HP + h + 1) * WP + wside) * CI + i0 + (q << 3)] = z4;
  }
  if (h == 0) {
    for (int idx = t; idx < 2 * 66 * 8; idx += 256) {
      const int row = (idx < 528) ? 0 : 65;
      const int rem = (idx < 528) ? idx : idx - 528;
      const int wz = rem >> 3;
      const int q = rem & 7;
      *(uint4*)&xs[((size_t)(b * HP + row) * WP + wz) * CI + i0 + (q << 3)] = z4;
    }
  }
  __syncthreads();
  const int w2 = t >> 2;
  const int q = t & 3;
  const uint4* src = (const uint4*)&lds[w2 * 72 + (q << 4)];
  const uint4 v0 = src[0];
  const uint4 v1 = src[1];
  u16* dst = xs + ((size_t)(b * HP + h + 1) * WP + (w2 + 1)) * CI + i0 + (q << 4);
  *(uint4*)dst = v0;
  *((uint4*)dst + 1) = v1;
}

// ---------------------------------------------------------------------------
// implicit-GEMM conv, LEVELED 4-phase schedule, MFMA 16x16x32 bf16.
// BM=256 (O), BN=256 (pixels), BK=64, 72 K-tiles. 512 thr, 8 waves (2Mx4N).
// Reads per phase leveled to 8/4/8/4 (was 12/4/8/0): next tile's B0 fragment
// pre-read in ph4's empty slot AFTER its MFMA (b0 WAR-safe), certified by
// vmcnt(6) at ph3 (completes SB(T+1); SA(T+1)+SB(T+2,h0) stay in flight).
// Staging per tile: SA(T+1)@ph1,2 (buf nb), SB(T+2)@ph3,4 (buf c).
// vmcnt(4) at ph4 certifies A(T+1) before next ph1. Natural block order
// (R11 showed mt-outer swizzle doubles FETCH).
// ---------------------------------------------------------------------------
__global__ __launch_bounds__(512, 2) void k_conv(
    const u16* __restrict__ xs, const u16* __restrict__ wb,
    const float* __restrict__ dmod, const float* __restrict__ bias,
    float* __restrict__ out)
{
  __shared__ __align__(16) u16 lA[2 * 16384];
  __shared__ __align__(16) u16 lB[2 * 16384];

  const int blk = blockIdx.x;
  const int nt = blk & 15;
  const int mt = (blk >> 4) & 1;
  const int b  = blk >> 5;
  const int ob = mt << 8;
  const int p0 = nt << 8;

  const int tid = threadIdx.x;
  const int wid = tid >> 6;
  const int lane = tid & 63;
  const int col = lane & 15;
  const int k8  = lane >> 4;
  const int wr  = wid >> 2;          // wave M index (0..1)
  const int wc  = wid & 3;           // wave N index (0..3)

  // staging lane geometry: each gload16 stages 8 rows x 8 slots (1 KB).
  // source column pre-swizzled: lane l fetches slot (l&7)^(l>>3) of its row.
  const int lr = lane >> 3;
  const int ls = lane & 7;
  const int swz = ls ^ lr;

  u32 aoff[4], boff[4], ldst[4];
  #pragma unroll
  for (int h2 = 0; h2 < 4; ++h2) {
    const int rowBase = ((h2 >> 1) << 7) + (wid << 4) + ((h2 & 1) << 3);
    const int rowIdx = rowBase + lr;
    aoff[h2] = (u32)((ob + rowIdx) * 4608 + (swz << 3));
    const int p = p0 + rowIdx;
    boff[h2] = (u32)(((b * HP + (p >> 6)) * WP + (p & 63)) * 512 + (swz << 3));
    ldst[h2] = (u32)(rowBase << 6);
  }

  // ds_read swizzled slot offsets: slot (kk*4+k8) ^ (row&7), row&7 == col&7
  const u32 sA0 = (u32)(((0 + k8) ^ (col & 7)) << 3);
  const u32 sA1 = (u32)(((4 + k8) ^ (col & 7)) << 3);
  const u32 aRead = (u32)((((wr << 7) + col) << 6));
  const u32 bRead = (u32)((((wc << 6) + col) << 6));

  floatx4 acc[8][4];
  #pragma unroll
  for (int m = 0; m < 8; ++m)
    #pragma unroll
    for (int n = 0; n < 4; ++n)
      acc[m][n] = (floatx4){0.f, 0.f, 0.f, 0.f};

  short8 a0[4][2], b0[2][2], b1[2][2];

#define SA(TILE, H, BUF) do {                                                 \
    const u32 at_ = (u32)((TILE) << 6);                                       \
    gload16(wb + aoff[(H)*2+0] + at_, &lA[((BUF) << 14) + ldst[(H)*2+0]]);    \
    gload16(wb + aoff[(H)*2+1] + at_, &lA[((BUF) << 14) + ldst[(H)*2+1]]);    \
  } while (0)

#define SB(TILE, H, BUF) do {                                                 \
    const int t_ = (TILE);                                                    \
    const int tap_ = t_ >> 3;                                                 \
    const int kh_ = tap_ / 3;                                                 \
    const int kw_ = tap_ - kh_ * 3;                                           \
    const u32 bt_ = (u32)(((kh_ * WP + kw_) << 9) + ((t_ & 7) << 6));         \
    gload16(xs + boff[(H)*2+0] + bt_, &lB[((BUF) << 14) + ldst[(H)*2+0]]);    \
    gload16(xs + boff[(H)*2+1] + bt_, &lB[((BUF) << 14) + ldst[(H)*2+1]]);    \
  } while (0)

#define READ_A(PA, MH) do {                                                   \
    _Pragma("unroll")                                                         \
    for (int mq = 0; mq < 4; ++mq) {                                          \
      a0[mq][0] = *(const short8*)((PA) + (MH) * 4096 + mq * 1024 + sA0);     \
      a0[mq][1] = *(const short8*)((PA) + (MH) * 4096 + mq * 1024 + sA1);     \
    }                                                                         \
  } while (0)

#define READ_B(PB, NH, BV) do {                                               \
    _Pragma("unroll")                                                         \
    for (int nq = 0; nq < 2; ++nq) {                                          \
      BV[nq][0] = *(const short8*)((PB) + (NH) * 2048 + nq * 1024 + sA0);     \
      BV[nq][1] = *(const short8*)((PB) + (NH) * 2048 + nq * 1024 + sA1);     \
    }                                                                         \
  } while (0)

#define MFMA_Q(MH, NH, BV) do {                                               \
    _Pragma("unroll")                                                         \
    for (int kk = 0; kk < 2; ++kk)                                            \
      _Pragma("unroll")                                                       \
      for (int nq = 0; nq < 2; ++nq)                                          \
        _Pragma("unroll")                                                     \
        for (int mq = 0; mq < 4; ++mq)                                        \
          acc[(MH)*4+mq][(NH)*2+nq] = __builtin_amdgcn_mfma_f32_16x16x32_bf16(\
              a0[mq][kk], BV[nq][kk], acc[(MH)*4+mq][(NH)*2+nq], 0, 0, 0);    \
  } while (0)

#define SBAR __builtin_amdgcn_s_barrier()
#define SCH0 __builtin_amdgcn_sched_barrier(0)
#define PRI1 __builtin_amdgcn_s_setprio(1)
#define PRI0 __builtin_amdgcn_s_setprio(0)

// MODE: 2 = full (tiles 0..69), 1 = tile 70, 0 = tile 71.
#define TILE4(T, C, MODE) do {                                                \
    const u16* pA  = lA + ((C) << 14) + aRead;                                \
    const u16* pB  = lB + ((C) << 14) + bRead;                                \
    const u16* pBn = lB + ((1 - (C)) << 14) + bRead;                          \
    /* ph1: 8 reads (A0); stage SA(T+1,h0); MFMA Q(0,0) on pre-read b0 */     \
    READ_A(pA, 0);                                                            \
    SCH0; if (MODE >= 1) SA((T) + 1, 0, 1 - (C));                             \
    SBAR; PRI1; MFMA_Q(0, 0, b0); PRI0; SBAR;                                 \
    /* ph2: 4 reads (B1); stage SA(T+1,h1) */                                 \
    READ_B(pB, 1, b1);                                                        \
    SCH0; if (MODE >= 1) SA((T) + 1, 1, 1 - (C));                             \
    SBAR; PRI1; MFMA_Q(0, 1, b1); PRI0; SBAR;                                 \
    /* ph3: 8 reads (A1); stage SB(T+2,h0); vmcnt certifies B(T+1) */         \
    READ_A(pA, 1);                                                            \
    SCH0; if (MODE == 2) SB((T) + 2, 0, C);                                   \
    if (MODE == 2)      asm volatile("s_waitcnt vmcnt(6)" ::: "memory");      \
    else if (MODE == 1) asm volatile("s_waitcnt vmcnt(4)" ::: "memory");      \
    SBAR; PRI1; MFMA_Q(1, 1, b1); PRI0; SBAR;                                 \
    /* ph4: stage SB(T+2,h1); vmcnt certifies A(T+1); MFMA Q(1,0);            \
       then pre-read NEXT tile's B0 (b0 dead after this MFMA) */              \
    SCH0; if (MODE == 2) SB((T) + 2, 1, C);                                   \
    if (MODE == 2)      asm volatile("s_waitcnt vmcnt(4)" ::: "memory");      \
    else if (MODE == 1) asm volatile("s_waitcnt vmcnt(0)" ::: "memory");      \
    SBAR; PRI1; MFMA_Q(1, 0, b0); PRI0;                                       \
    if (MODE >= 1) READ_B(pBn, 0, b0);                                        \
    SBAR;                                                                     \
  } while (0)

  // prologue: SB(0), SA(0) [oldest 8], SB(1) [newest 4];
  // vmcnt(4) completes SB(0)+SA(0), leaves SB(1) in flight (steady invariant).
  SB(0, 0, 0); SB(0, 1, 0);
  SA(0, 0, 0); SA(0, 1, 0);
  SB(1, 0, 1); SB(1, 1, 1);
  asm volatile("s_waitcnt vmcnt(4)" ::: "memory");
  SCH0;
  SBAR;
  {
    const u16* pB0 = lB + bRead;
    READ_B(pB0, 0, b0);              // pre-read B0 of tile 0
  }

  for (int j = 0; j < 35; ++j) {
    TILE4(2 * j,     0, 2);
    TILE4(2 * j + 1, 1, 2);
  }
  TILE4(70, 0, 1);
  TILE4(71, 1, 0);

#undef SA
#undef SB
#undef READ_A
#undef READ_B
#undef MFMA_Q
#undef TILE4
#undef SBAR
#undef SCH0
#undef PRI1
#undef PRI0

  // epilogue: out = acc * d[b,o] + bias[o]; C/D: col=lane&15, row=(lane>>4)*4+r
  #pragma unroll
  for (int m = 0; m < 8; ++m) {
    #pragma unroll
    for (int r = 0; r < 4; ++r) {
      const int o = ob + (wr << 7) + (m << 4) + (k8 << 2) + r;
      const float dm = dmod[b * CO + o];
      const float bs = bias[o];
      float* po = out + (((size_t)(b * CO + o)) << 12) + p0 + (wc << 6);
      #pragma unroll
      for (int n = 0; n < 4; ++n)
        po[(n << 4) + col] = acc[m][n][r] * dm + bs;
    }
  }
}

extern "C" void kernel_launch(void* const* d_in, const int* in_sizes, int n_in,
                              void* d_out, int out_size, void* d_ws, size_t ws_size,
                              hipStream_t stream) {
  const float* x    = (const float*)d_in[0];
  const float* y    = (const float*)d_in[1];
  const float* aw   = (const float*)d_in[2];
  const float* ab   = (const float*)d_in[3];
  const float* wt   = (const float*)d_in[4];
  const float* bias = (const float*)d_in[5];
  float* out = (float*)d_out;

  char* ws = (char*)d_ws;
  const size_t XS_BYTES = (size_t)NB * HP * WP * CI * 2;     // 35,684,352
  const size_t WB_BYTES = (size_t)CO * 9 * CI * 2;           //  4,718,592
  const size_t WS_BYTES = (size_t)CO * CI * 4;               //  1,048,576
  u16* xsb    = (u16*)ws;
  u16* wbuf   = (u16*)(ws + XS_BYTES);
  float* wsum = (float*)(ws + XS_BYTES + WB_BYTES);
  float* sbuf = (float*)(ws + XS_BYTES + WB_BYTES + WS_BYTES);
  float* dbuf = sbuf + NB * CI;

  k_prep1<<<dim3(2048), dim3(256), 0, stream>>>(y, aw, ab, sbuf, wt, wsum, wbuf);
  k_xfd  <<<dim3(5120), dim3(256), 0, stream>>>(x, sbuf, xsb, wsum, dbuf);
  k_conv <<<dim3(256), dim3(512), 0, stream>>>(xsb, wbuf, dbuf, bias, out);
}

// Round 13
// 153.043 us; speedup vs baseline: 1.2385x; 1.0078x over previous
//
#include <hip/hip_runtime.h>

typedef __attribute__((ext_vector_type(8))) short short8;
typedef __attribute__((ext_vector_type(4))) float floatx4;
typedef unsigned short u16;
typedef unsigned int u32;

#define NB 8
#define CI 512
#define CO 512
#define HH 64
#define WW 64
#define HP 66
#define WP 66
#define BK 64

__device__ __forceinline__ u16 f2bf(float f) {
  u32 u = __builtin_bit_cast(u32, f);
  u += 0x7fffu + ((u >> 16) & 1u);
  return (u16)(u >> 16);
}

__device__ __forceinline__ void gload16(const void* g, void* l) {
  __builtin_amdgcn_global_load_lds(
      (const __attribute__((address_space(1))) unsigned int*)g,
      (__attribute__((address_space(3))) unsigned int*)l, 16, 0, 0);
}

// fused prep1: blocks 0..1023 -> style s[b,i]; blocks 1024..2047 -> wprep.
__global__ __launch_bounds__(256) void k_prep1(
    const float* __restrict__ y, const float* __restrict__ aw,
    const float* __restrict__ ab, float* __restrict__ s,
    const float* __restrict__ wt, float* __restrict__ wsum,
    u16* __restrict__ wbv)
{
  if (blockIdx.x < 1024) {
    const int wid = blockIdx.x * 4 + (threadIdx.x >> 6);
    const int lane = threadIdx.x & 63;
    const int b = wid >> 9, i = wid & 511;
    float sum = 0.f;
    #pragma unroll
    for (int j = 0; j < 8; ++j) {
      const int k = lane + (j << 6);
      sum += y[b * CI + k] * aw[i * CI + k];
    }
    #pragma unroll
    for (int off = 32; off; off >>= 1) sum += __shfl_xor(sum, off);
    if (lane == 0) s[wid] = sum * 0.044194173824159216f + ab[i] + 1.0f;
  } else {
    const int idx = (blockIdx.x - 1024) * 256 + threadIdx.x;   // o*512+i
    const int i = idx & 511;
    const int o = idx >> 9;
    const float* p = wt + (size_t)idx * 9;
    float v[9];
    float sum = 0.f;
    #pragma unroll
    for (int t = 0; t < 9; ++t) { v[t] = p[t]; sum += v[t] * v[t]; }
    wsum[idx] = sum;
    #pragma unroll
    for (int t = 0; t < 9; ++t) wbv[(((o * 9 + t) << 9) | i)] = f2bf(v[t]);
  }
}

// fused: blocks 0..4095 -> xform (xs build + halo zero); 4096..5119 -> demod.
__global__ __launch_bounds__(256) void k_xfd(
    const float* __restrict__ x, const float* __restrict__ s,
    u16* __restrict__ xs, const float* __restrict__ wsum,
    float* __restrict__ d)
{
  __shared__ __align__(16) u16 lds[64 * 72];
  if (blockIdx.x >= 4096) {
    const int wid = (blockIdx.x - 4096) * 4 + (threadIdx.x >> 6);
    const int lane = threadIdx.x & 63;
    const int b = wid >> 9, o = wid & 511;
    float sum = 0.f;
    #pragma unroll
    for (int j = 0; j < 8; ++j) {
      const int i = lane + (j << 6);
      const float sv = s[b * CI + i];
      sum += wsum[o * CI + i] * sv * sv;
    }
    #pragma unroll
    for (int off = 32; off; off >>= 1) sum += __shfl_xor(sum, off);
    if (lane == 0) d[wid] = rsqrtf(sum + 1e-4f);
    return;
  }
  const int blk = blockIdx.x;          // ((b*64+h)*8 + ic)
  const int ic = blk & 7;
  const int h = (blk >> 3) & 63;
  const int b = blk >> 9;
  const int i0 = ic << 6;
  const int t = threadIdx.x;
  const int w = t & 63;
  const int i4 = t >> 6;
  #pragma unroll
  for (int p = 0; p < 16; ++p) {
    const int ii = i4 + (p << 2);
    const float xv = x[((size_t)(b * CI + i0 + ii) * HH + h) * WW + w];
    const float sv = s[b * CI + i0 + ii];
    lds[w * 72 + ii] = f2bf(xv * sv);
  }
  const uint4 z4 = {0u, 0u, 0u, 0u};
  if (t < 16) {
    const int wside = (t < 8) ? 0 : 65;
    const int q = t & 7;
    *(uint4*)&xs[((size_t)(b * HP + h + 1) * WP + wside) * CI + i0 + (q << 3)] = z4;
  }
  if (h == 0) {
    for (int idx = t; idx < 2 * 66 * 8; idx += 256) {
      const int row = (idx < 528) ? 0 : 65;
      const int rem = (idx < 528) ? idx : idx - 528;
      const int wz = rem >> 3;
      const int q = rem & 7;
      *(uint4*)&xs[((size_t)(b * HP + row) * WP + wz) * CI + i0 + (q << 3)] = z4;
    }
  }
  __syncthreads();
  const int w2 = t >> 2;
  const int q = t & 3;
  const uint4* src = (const uint4*)&lds[w2 * 72 + (q << 4)];
  const uint4 v0 = src[0];
  const uint4 v1 = src[1];
  u16* dst = xs + ((size_t)(b * HP + h + 1) * WP + (w2 + 1)) * CI + i0 + (q << 4);
  *(uint4*)dst = v0;
  *((uint4*)dst + 1) = v1;
}

// ---------------------------------------------------------------------------
// implicit-GEMM conv, leveled 4-phase schedule + m201 wait discipline:
// explicit s_waitcnt lgkmcnt(0) + sched_barrier(0) AFTER each pre-MFMA
// barrier, BEFORE setprio(1). Mechanism: compiler-counted lgkm waits
// interleave inside the MFMA cluster, so a wave holds prio 1 while stalled
// on LDS; draining once post-barrier (reads completed during barrier wait)
// makes the 16-MFMA cluster issue wait-free. Everything else = R12.
// ---------------------------------------------------------------------------
__global__ __launch_bounds__(512, 2) void k_conv(
    const u16* __restrict__ xs, const u16* __restrict__ wb,
    const float* __restrict__ dmod, const float* __restrict__ bias,
    float* __restrict__ out)
{
  __shared__ __align__(16) u16 lA[2 * 16384];
  __shared__ __align__(16) u16 lB[2 * 16384];

  const int blk = blockIdx.x;
  const int nt = blk & 15;
  const int mt = (blk >> 4) & 1;
  const int b  = blk >> 5;
  const int ob = mt << 8;
  const int p0 = nt << 8;

  const int tid = threadIdx.x;
  const int wid = tid >> 6;
  const int lane = tid & 63;
  const int col = lane & 15;
  const int k8  = lane >> 4;
  const int wr  = wid >> 2;          // wave M index (0..1)
  const int wc  = wid & 3;           // wave N index (0..3)

  // staging lane geometry: each gload16 stages 8 rows x 8 slots (1 KB).
  // source column pre-swizzled: lane l fetches slot (l&7)^(l>>3) of its row.
  const int lr = lane >> 3;
  const int ls = lane & 7;
  const int swz = ls ^ lr;

  u32 aoff[4], boff[4], ldst[4];
  #pragma unroll
  for (int h2 = 0; h2 < 4; ++h2) {
    const int rowBase = ((h2 >> 1) << 7) + (wid << 4) + ((h2 & 1) << 3);
    const int rowIdx = rowBase + lr;
    aoff[h2] = (u32)((ob + rowIdx) * 4608 + (swz << 3));
    const int p = p0 + rowIdx;
    boff[h2] = (u32)(((b * HP + (p >> 6)) * WP + (p & 63)) * 512 + (swz << 3));
    ldst[h2] = (u32)(rowBase << 6);
  }

  // ds_read swizzled slot offsets: slot (kk*4+k8) ^ (row&7), row&7 == col&7
  const u32 sA0 = (u32)(((0 + k8) ^ (col & 7)) << 3);
  const u32 sA1 = (u32)(((4 + k8) ^ (col & 7)) << 3);
  const u32 aRead = (u32)((((wr << 7) + col) << 6));
  const u32 bRead = (u32)((((wc << 6) + col) << 6));

  floatx4 acc[8][4];
  #pragma unroll
  for (int m = 0; m < 8; ++m)
    #pragma unroll
    for (int n = 0; n < 4; ++n)
      acc[m][n] = (floatx4){0.f, 0.f, 0.f, 0.f};

  short8 a0[4][2], b0[2][2], b1[2][2];

#define SA(TILE, H, BUF) do {                                                 \
    const u32 at_ = (u32)((TILE) << 6);                                       \
    gload16(wb + aoff[(H)*2+0] + at_, &lA[((BUF) << 14) + ldst[(H)*2+0]]);    \
    gload16(wb + aoff[(H)*2+1] + at_, &lA[((BUF) << 14) + ldst[(H)*2+1]]);    \
  } while (0)

#define SB(TILE, H, BUF) do {                                                 \
    const int t_ = (TILE);                                                    \
    const int tap_ = t_ >> 3;                                                 \
    const int kh_ = tap_ / 3;                                                 \
    const int kw_ = tap_ - kh_ * 3;                                           \
    const u32 bt_ = (u32)(((kh_ * WP + kw_) << 9) + ((t_ & 7) << 6));         \
    gload16(xs + boff[(H)*2+0] + bt_, &lB[((BUF) << 14) + ldst[(H)*2+0]]);    \
    gload16(xs + boff[(H)*2+1] + bt_, &lB[((BUF) << 14) + ldst[(H)*2+1]]);    \
  } while (0)

#define READ_A(PA, MH) do {                                                   \
    _Pragma("unroll")                                                         \
    for (int mq = 0; mq < 4; ++mq) {                                          \
      a0[mq][0] = *(const short8*)((PA) + (MH) * 4096 + mq * 1024 + sA0);     \
      a0[mq][1] = *(const short8*)((PA) + (MH) * 4096 + mq * 1024 + sA1);     \
    }                                                                         \
  } while (0)

#define READ_B(PB, NH, BV) do {                                               \
    _Pragma("unroll")                                                         \
    for (int nq = 0; nq < 2; ++nq) {                                          \
      BV[nq][0] = *(const short8*)((PB) + (NH) * 2048 + nq * 1024 + sA0);     \
      BV[nq][1] = *(const short8*)((PB) + (NH) * 2048 + nq * 1024 + sA1);     \
    }                                                                         \
  } while (0)

#define MFMA_Q(MH, NH, BV) do {                                               \
    _Pragma("unroll")                                                         \
    for (int kk = 0; kk < 2; ++kk)                                            \
      _Pragma("unroll")                                                       \
      for (int nq = 0; nq < 2; ++nq)                                          \
        _Pragma("unroll")                                                     \
        for (int mq = 0; mq < 4; ++mq)                                        \
          acc[(MH)*4+mq][(NH)*2+nq] = __builtin_amdgcn_mfma_f32_16x16x32_bf16(\
              a0[mq][kk], BV[nq][kk], acc[(MH)*4+mq][(NH)*2+nq], 0, 0, 0);    \
  } while (0)

#define SBAR __builtin_amdgcn_s_barrier()
#define SCH0 __builtin_amdgcn_sched_barrier(0)
#define PRI1 __builtin_amdgcn_s_setprio(1)
#define PRI0 __builtin_amdgcn_s_setprio(0)
// m201 wait discipline: drain LDS-read counter once, post-barrier, then a
// sched fence (rule 18: hipcc hoists reg-only MFMA past inline-asm lgkmcnt).
#define LGKM0 do { asm volatile("s_waitcnt lgkmcnt(0)" ::: "memory"); SCH0; } while (0)

// MODE: 2 = full (tiles 0..69), 1 = tile 70, 0 = tile 71.
#define TILE4(T, C, MODE) do {                                                \
    const u16* pA  = lA + ((C) << 14) + aRead;                                \
    const u16* pB  = lB + ((C) << 14) + bRead;                                \
    const u16* pBn = lB + ((1 - (C)) << 14) + bRead;                          \
    /* ph1: 8 reads (A0); stage SA(T+1,h0); MFMA Q(0,0) on pre-read b0 */     \
    READ_A(pA, 0);                                                            \
    SCH0; if (MODE >= 1) SA((T) + 1, 0, 1 - (C));                             \
    SBAR; LGKM0; PRI1; MFMA_Q(0, 0, b0); PRI0; SBAR;                          \
    /* ph2: 4 reads (B1); stage SA(T+1,h1) */                                 \
    READ_B(pB, 1, b1);                                                        \
    SCH0; if (MODE >= 1) SA((T) + 1, 1, 1 - (C));                             \
    SBAR; LGKM0; PRI1; MFMA_Q(0, 1, b1); PRI0; SBAR;                          \
    /* ph3: 8 reads (A1); stage SB(T+2,h0); vmcnt certifies B(T+1) */         \
    READ_A(pA, 1);                                                            \
    SCH0; if (MODE == 2) SB((T) + 2, 0, C);                                   \
    if (MODE == 2)      asm volatile("s_waitcnt vmcnt(6)" ::: "memory");      \
    else if (MODE == 1) asm volatile("s_waitcnt vmcnt(4)" ::: "memory");      \
    SBAR; LGKM0; PRI1; MFMA_Q(1, 1, b1); PRI0; SBAR;                          \
    /* ph4: stage SB(T+2,h1); vmcnt certifies A(T+1); MFMA Q(1,0);            \
       then pre-read NEXT tile's B0 (b0 dead after this MFMA) */              \
    SCH0; if (MODE == 2) SB((T) + 2, 1, C);                                   \
    if (MODE == 2)      asm volatile("s_waitcnt vmcnt(4)" ::: "memory");      \
    else if (MODE == 1) asm volatile("s_waitcnt vmcnt(0)" ::: "memory");      \
    SBAR; LGKM0; PRI1; MFMA_Q(1, 0, b0); PRI0;                                \
    if (MODE >= 1) READ_B(pBn, 0, b0);                                        \
    SBAR;                                                                     \
  } while (0)

  // prologue: SB(0), SA(0) [oldest 8], SB(1) [newest 4];
  // vmcnt(4) completes SB(0)+SA(0), leaves SB(1) in flight (steady invariant).
  SB(0, 0, 0); SB(0, 1, 0);
  SA(0, 0, 0); SA(0, 1, 0);
  SB(1, 0, 1); SB(1, 1, 1);
  asm volatile("s_waitcnt vmcnt(4)" ::: "memory");
  SCH0;
  SBAR;
  {
    const u16* pB0 = lB + bRead;
    READ_B(pB0, 0, b0);              // pre-read B0 of tile 0
  }

  for (int j = 0; j < 35; ++j) {
    TILE4(2 * j,     0, 2);
    TILE4(2 * j + 1, 1, 2);
  }
  TILE4(70, 0, 1);
  TILE4(71, 1, 0);

#undef SA
#undef SB
#undef READ_A
#undef READ_B
#undef MFMA_Q
#undef TILE4
#undef SBAR
#undef SCH0
#undef PRI1
#undef PRI0
#undef LGKM0

  // epilogue: out = acc * d[b,o] + bias[o]; C/D: col=lane&15, row=(lane>>4)*4+r
  #pragma unroll
  for (int m = 0; m < 8; ++m) {
    #pragma unroll
    for (int r = 0; r < 4; ++r) {
      const int o = ob + (wr << 7) + (m << 4) + (k8 << 2) + r;
      const float dm = dmod[b * CO + o];
      const float bs = bias[o];
      float* po = out + (((size_t)(b * CO + o)) << 12) + p0 + (wc << 6);
      #pragma unroll
      for (int n = 0; n < 4; ++n)
        po[(n << 4) + col] = acc[m][n][r] * dm + bs;
    }
  }
}

extern "C" void kernel_launch(void* const* d_in, const int* in_sizes, int n_in,
                              void* d_out, int out_size, void* d_ws, size_t ws_size,
                              hipStream_t stream) {
  const float* x    = (const float*)d_in[0];
  const float* y    = (const float*)d_in[1];
  const float* aw   = (const float*)d_in[2];
  const float* ab   = (const float*)d_in[3];
  const float* wt   = (const float*)d_in[4];
  const float* bias = (const float*)d_in[5];
  float* out = (float*)d_out;

  char* ws = (char*)d_ws;
  const size_t XS_BYTES = (size_t)NB * HP * WP * CI * 2;     // 35,684,352
  const size_t WB_BYTES = (size_t)CO * 9 * CI * 2;           //  4,718,592
  const size_t WS_BYTES = (size_t)CO * CI * 4;               //  1,048,576
  u16* xsb    = (u16*)ws;
  u16* wbuf   = (u16*)(ws + XS_BYTES);
  float* wsum = (float*)(ws + XS_BYTES + WB_BYTES);
  float* sbuf = (float*)(ws + XS_BYTES + WB_BYTES + WS_BYTES);
  float* dbuf = sbuf + NB * CI;

  k_prep1<<<dim3(2048), dim3(256), 0, stream>>>(y, aw, ab, sbuf, wt, wsum, wbuf);
  k_xfd  <<<dim3(5120), dim3(256), 0, stream>>>(x, sbuf, xsb, wsum, dbuf);
  k_conv <<<dim3(256), dim3(512), 0, stream>>>(xsb, wbuf, dbuf, bias, out);
}